// Round 1
// baseline (787.166 us; speedup 1.0000x reference)
//
#include <hip/hip_runtime.h>

// Problem constants (fixed by reference setup_inputs):
//   x:   (8, 3, 1024, 1024) float32
//   LUT: (3, 33, 33, 33)    float32
//   out: (8, 3, 1024, 1024) float32
constexpr int D      = 33;
constexpr int LUTSZ  = D * D * D;      // 35937 elements per channel
constexpr int PLANE  = 1024 * 1024;    // H*W = 2^20
constexpr int BATCH  = 8;

__device__ __forceinline__ void apply_lut(const float* __restrict__ lut,
                                          float r, float g, float b,
                                          float& o0, float& o1, float& o2)
{
    // t = clip(x * (D-1), 0, D-1)
    float tr = fminf(fmaxf(r * 32.0f, 0.0f), 32.0f);
    float tg = fminf(fmaxf(g * 32.0f, 0.0f), 32.0f);
    float tb = fminf(fmaxf(b * 32.0f, 0.0f), 32.0f);

    float fk = floorf(tr); int k0 = (int)fk; float wk = tr - fk;  // from channel 0 (r)
    float fj = floorf(tg); int j0 = (int)fj; float wj = tg - fj;  // from channel 1 (g)
    float fi = floorf(tb); int i0 = (int)fi; float wi = tb - fi;  // from channel 2 (b)

    int k1 = min(k0 + 1, D - 1);
    int j1 = min(j0 + 1, D - 1);
    int i1 = min(i0 + 1, D - 1);

    // idx = (i*D + j)*D + k
    int b00 = (i0 * D + j0) * D;
    int b01 = (i0 * D + j1) * D;
    int b10 = (i1 * D + j0) * D;
    int b11 = (i1 * D + j1) * D;

    float* outs[3] = { &o0, &o1, &o2 };
#pragma unroll
    for (int c = 0; c < 3; ++c) {
        const float* __restrict__ L = lut + c * LUTSZ;
        float a00 = L[b00 + k0], a00b = L[b00 + k1];
        float a01 = L[b01 + k0], a01b = L[b01 + k1];
        float a10 = L[b10 + k0], a10b = L[b10 + k1];
        float a11 = L[b11 + k0], a11b = L[b11 + k1];
        float c00 = fmaf(wk, a00b - a00, a00);
        float c01 = fmaf(wk, a01b - a01, a01);
        float c10 = fmaf(wk, a10b - a10, a10);
        float c11 = fmaf(wk, a11b - a11, a11);
        float c0  = fmaf(wj, c01 - c00, c00);
        float c1  = fmaf(wj, c11 - c10, c10);
        *outs[c]  = fmaf(wi, c1 - c0, c0);
    }
}

__global__ __launch_bounds__(256)
void lut3d_kernel(const float* __restrict__ x,
                  const float* __restrict__ lut,
                  float* __restrict__ out)
{
    const int tid = blockIdx.x * blockDim.x + threadIdx.x;
    const int p0  = tid << 2;                 // first of 4 consecutive pixels
    const int b   = p0 >> 20;                 // PLANE = 2^20
    const int q   = p0 & (PLANE - 1);
    const int base = b * 3 * PLANE + q;       // max ~25.1M, fits int

    const float4 rv = *reinterpret_cast<const float4*>(x + base);
    const float4 gv = *reinterpret_cast<const float4*>(x + base + PLANE);
    const float4 bv = *reinterpret_cast<const float4*>(x + base + 2 * PLANE);

    float4 o0, o1, o2;
    apply_lut(lut, rv.x, gv.x, bv.x, o0.x, o1.x, o2.x);
    apply_lut(lut, rv.y, gv.y, bv.y, o0.y, o1.y, o2.y);
    apply_lut(lut, rv.z, gv.z, bv.z, o0.z, o1.z, o2.z);
    apply_lut(lut, rv.w, gv.w, bv.w, o0.w, o1.w, o2.w);

    *reinterpret_cast<float4*>(out + base)             = o0;
    *reinterpret_cast<float4*>(out + base + PLANE)     = o1;
    *reinterpret_cast<float4*>(out + base + 2 * PLANE) = o2;
}

extern "C" void kernel_launch(void* const* d_in, const int* in_sizes, int n_in,
                              void* d_out, int out_size, void* d_ws, size_t ws_size,
                              hipStream_t stream)
{
    const float* x   = (const float*)d_in[0];   // (8,3,1024,1024) fp32
    const float* lut = (const float*)d_in[1];   // (3,33,33,33)    fp32
    float* out       = (float*)d_out;           // (8,3,1024,1024) fp32

    const int total_pixels = BATCH * PLANE;     // 8,388,608
    const int n_threads    = total_pixels / 4;  // 2,097,152
    dim3 block(256);
    dim3 grid(n_threads / 256);                 // 8192 blocks
    lut3d_kernel<<<grid, block, 0, stream>>>(x, lut, out);
}

// Round 4
// 285.579 us; speedup vs baseline: 2.7564x; 2.7564x over previous
//
#include <hip/hip_runtime.h>
#include <hip/hip_fp16.h>

// Problem constants (fixed by reference setup_inputs):
//   x:   (8, 3, 1024, 1024) float32
//   LUT: (3, 33, 33, 33)    float32
//   out: (8, 3, 1024, 1024) float32
constexpr int D      = 33;
constexpr int LUTSZ  = D * D * D;      // 35937 elements per channel
constexpr int PLANE  = 1024 * 1024;    // H*W = 2^20
constexpr int BATCH  = 8;
constexpr size_t PACKED_BYTES = (size_t)LUTSZ * 16;   // 574,992 B

// Native clang vector types — required for __builtin_nontemporal_{load,store}
typedef float        v4f __attribute__((ext_vector_type(4)));
typedef unsigned int v4u __attribute__((ext_vector_type(4)));

struct Rgb { float c0, c1, c2; };

// ---------------------------------------------------------------------------
// Pack kernel: P[idx] = fp16{L0[idx],L0[idx+1], L1[idx],L1[idx+1], L2[idx],L2[idx+1]}
// Only entries with k<32 are ever gathered (k0 clamped to 31); k==32 entries
// are zero-filled for determinism.
// ---------------------------------------------------------------------------
__global__ __launch_bounds__(256)
void pack_lut_kernel(const float* __restrict__ lut, v4u* __restrict__ P)
{
    int idx = blockIdx.x * blockDim.x + threadIdx.x;
    if (idx >= LUTSZ) return;
    int k = idx % D;
    v4u e = (v4u)(0u);
    if (k < D - 1) {
        __half2 h0 = __floats2half2_rn(lut[0 * LUTSZ + idx], lut[0 * LUTSZ + idx + 1]);
        __half2 h1 = __floats2half2_rn(lut[1 * LUTSZ + idx], lut[1 * LUTSZ + idx + 1]);
        __half2 h2 = __floats2half2_rn(lut[2 * LUTSZ + idx], lut[2 * LUTSZ + idx + 1]);
        e.x = *reinterpret_cast<unsigned int*>(&h0);
        e.y = *reinterpret_cast<unsigned int*>(&h1);
        e.z = *reinterpret_cast<unsigned int*>(&h2);
    }
    P[idx] = e;
}

__device__ __forceinline__ float lerp_h2(unsigned int u, float w)
{
    __half2 h = *reinterpret_cast<__half2*>(&u);
    float lo = __half2float(__low2half(h));
    float hi = __half2float(__high2half(h));
    return fmaf(w, hi - lo, lo);
}

__device__ __forceinline__ Rgb apply_lut_packed(const v4u* __restrict__ P,
                                                float r, float g, float b)
{
    float tr = fminf(fmaxf(r * 32.0f, 0.0f), 32.0f);
    float tg = fminf(fmaxf(g * 32.0f, 0.0f), 32.0f);
    float tb = fminf(fmaxf(b * 32.0f, 0.0f), 32.0f);

    // k handled via packed pair: clamp k0 to 31 so (k0,k0+1) is always valid.
    // t==32 -> k0=31, wk=1.0 reproduces L[32] exactly.
    int k0 = min((int)tr, D - 2);        // t>=0 so (int) == floor
    float wk = tr - (float)k0;
    int j0 = (int)tg; float wj = tg - (float)j0; int j1 = min(j0 + 1, D - 1);
    int i0 = (int)tb; float wi = tb - (float)i0; int i1 = min(i0 + 1, D - 1);

    int r00 = (i0 * D + j0) * D + k0;
    int r01 = (i0 * D + j1) * D + k0;
    int r10 = (i1 * D + j0) * D + k0;
    int r11 = (i1 * D + j1) * D + k0;

    v4u e00 = P[r00];
    v4u e01 = P[r01];
    v4u e10 = P[r10];
    v4u e11 = P[r11];

    Rgb o;
    {
        float c00 = lerp_h2(e00.x, wk), c01 = lerp_h2(e01.x, wk);
        float c10 = lerp_h2(e10.x, wk), c11 = lerp_h2(e11.x, wk);
        float c0 = fmaf(wj, c01 - c00, c00);
        float c1 = fmaf(wj, c11 - c10, c10);
        o.c0 = fmaf(wi, c1 - c0, c0);
    }
    {
        float c00 = lerp_h2(e00.y, wk), c01 = lerp_h2(e01.y, wk);
        float c10 = lerp_h2(e10.y, wk), c11 = lerp_h2(e11.y, wk);
        float c0 = fmaf(wj, c01 - c00, c00);
        float c1 = fmaf(wj, c11 - c10, c10);
        o.c1 = fmaf(wi, c1 - c0, c0);
    }
    {
        float c00 = lerp_h2(e00.z, wk), c01 = lerp_h2(e01.z, wk);
        float c10 = lerp_h2(e10.z, wk), c11 = lerp_h2(e11.z, wk);
        float c0 = fmaf(wj, c01 - c00, c00);
        float c1 = fmaf(wj, c11 - c10, c10);
        o.c2 = fmaf(wi, c1 - c0, c0);
    }
    return o;
}

__global__ __launch_bounds__(256)
void lut3d_packed_kernel(const float* __restrict__ x,
                         const v4u* __restrict__ P,
                         float* __restrict__ out)
{
    const int tid = blockIdx.x * blockDim.x + threadIdx.x;
    const int p0  = tid << 2;                 // 4 consecutive pixels
    const int b   = p0 >> 20;                 // PLANE = 2^20
    const int q   = p0 & (PLANE - 1);
    const int base = b * 3 * PLANE + q;

    // Non-temporal streaming loads: keep L2 for the packed LUT.
    const v4f rv = __builtin_nontemporal_load(reinterpret_cast<const v4f*>(x + base));
    const v4f gv = __builtin_nontemporal_load(reinterpret_cast<const v4f*>(x + base + PLANE));
    const v4f bv = __builtin_nontemporal_load(reinterpret_cast<const v4f*>(x + base + 2 * PLANE));

    Rgb p0r = apply_lut_packed(P, rv.x, gv.x, bv.x);
    Rgb p1r = apply_lut_packed(P, rv.y, gv.y, bv.y);
    Rgb p2r = apply_lut_packed(P, rv.z, gv.z, bv.z);
    Rgb p3r = apply_lut_packed(P, rv.w, gv.w, bv.w);

    v4f o0 = { p0r.c0, p1r.c0, p2r.c0, p3r.c0 };
    v4f o1 = { p0r.c1, p1r.c1, p2r.c1, p3r.c1 };
    v4f o2 = { p0r.c2, p1r.c2, p2r.c2, p3r.c2 };

    __builtin_nontemporal_store(o0, reinterpret_cast<v4f*>(out + base));
    __builtin_nontemporal_store(o1, reinterpret_cast<v4f*>(out + base + PLANE));
    __builtin_nontemporal_store(o2, reinterpret_cast<v4f*>(out + base + 2 * PLANE));
}

// ---------------------------------------------------------------------------
// Fallback (R1 kernel): direct fp32 gathers, only if ws_size is too small.
// ---------------------------------------------------------------------------
__device__ __forceinline__ Rgb apply_lut_direct(const float* __restrict__ lut,
                                                float r, float g, float b)
{
    float tr = fminf(fmaxf(r * 32.0f, 0.0f), 32.0f);
    float tg = fminf(fmaxf(g * 32.0f, 0.0f), 32.0f);
    float tb = fminf(fmaxf(b * 32.0f, 0.0f), 32.0f);
    int k0 = (int)tr; float wk = tr - (float)k0; int k1 = min(k0 + 1, D - 1);
    int j0 = (int)tg; float wj = tg - (float)j0; int j1 = min(j0 + 1, D - 1);
    int i0 = (int)tb; float wi = tb - (float)i0; int i1 = min(i0 + 1, D - 1);
    int b00 = (i0 * D + j0) * D, b01 = (i0 * D + j1) * D;
    int b10 = (i1 * D + j0) * D, b11 = (i1 * D + j1) * D;
    Rgb o;
    float* outs[3] = { &o.c0, &o.c1, &o.c2 };
#pragma unroll
    for (int c = 0; c < 3; ++c) {
        const float* __restrict__ L = lut + c * LUTSZ;
        float c00 = fmaf(wk, L[b00 + k1] - L[b00 + k0], L[b00 + k0]);
        float c01 = fmaf(wk, L[b01 + k1] - L[b01 + k0], L[b01 + k0]);
        float c10 = fmaf(wk, L[b10 + k1] - L[b10 + k0], L[b10 + k0]);
        float c11 = fmaf(wk, L[b11 + k1] - L[b11 + k0], L[b11 + k0]);
        float c0  = fmaf(wj, c01 - c00, c00);
        float c1  = fmaf(wj, c11 - c10, c10);
        *outs[c]  = fmaf(wi, c1 - c0, c0);
    }
    return o;
}

__global__ __launch_bounds__(256)
void lut3d_direct_kernel(const float* __restrict__ x,
                         const float* __restrict__ lut,
                         float* __restrict__ out)
{
    const int tid = blockIdx.x * blockDim.x + threadIdx.x;
    const int p0  = tid << 2;
    const int b   = p0 >> 20;
    const int q   = p0 & (PLANE - 1);
    const int base = b * 3 * PLANE + q;
    const v4f rv = *reinterpret_cast<const v4f*>(x + base);
    const v4f gv = *reinterpret_cast<const v4f*>(x + base + PLANE);
    const v4f bv = *reinterpret_cast<const v4f*>(x + base + 2 * PLANE);
    Rgb p0r = apply_lut_direct(lut, rv.x, gv.x, bv.x);
    Rgb p1r = apply_lut_direct(lut, rv.y, gv.y, bv.y);
    Rgb p2r = apply_lut_direct(lut, rv.z, gv.z, bv.z);
    Rgb p3r = apply_lut_direct(lut, rv.w, gv.w, bv.w);
    v4f o0 = { p0r.c0, p1r.c0, p2r.c0, p3r.c0 };
    v4f o1 = { p0r.c1, p1r.c1, p2r.c1, p3r.c1 };
    v4f o2 = { p0r.c2, p1r.c2, p2r.c2, p3r.c2 };
    *reinterpret_cast<v4f*>(out + base)             = o0;
    *reinterpret_cast<v4f*>(out + base + PLANE)     = o1;
    *reinterpret_cast<v4f*>(out + base + 2 * PLANE) = o2;
}

extern "C" void kernel_launch(void* const* d_in, const int* in_sizes, int n_in,
                              void* d_out, int out_size, void* d_ws, size_t ws_size,
                              hipStream_t stream)
{
    const float* x   = (const float*)d_in[0];   // (8,3,1024,1024) fp32
    const float* lut = (const float*)d_in[1];   // (3,33,33,33)    fp32
    float* out       = (float*)d_out;

    const int total_pixels = BATCH * PLANE;     // 8,388,608
    const int n_threads    = total_pixels / 4;  // 2,097,152
    dim3 block(256);
    dim3 grid(n_threads / 256);                 // 8192 blocks

    if (ws_size >= PACKED_BYTES) {
        v4u* P = (v4u*)d_ws;
        pack_lut_kernel<<<(LUTSZ + 255) / 256, 256, 0, stream>>>(lut, P);
        lut3d_packed_kernel<<<grid, block, 0, stream>>>(x, P, out);
    } else {
        lut3d_direct_kernel<<<grid, block, 0, stream>>>(x, lut, out);
    }
}

// Round 5
// 231.807 us; speedup vs baseline: 3.3958x; 1.2320x over previous
//
#include <hip/hip_runtime.h>
#include <hip/hip_fp16.h>

// Problem constants (fixed by reference setup_inputs):
//   x:   (8, 3, 1024, 1024) float32
//   LUT: (3, 33, 33, 33)    float32
//   out: (8, 3, 1024, 1024) float32
constexpr int D      = 33;
constexpr int LUTSZ  = D * D * D;       // 35937 per channel
constexpr int PLANE  = 1024 * 1024;     // 2^20
constexpr int BATCH  = 8;
constexpr int NCELL  = 32 * 32 * 32;    // 32768 interpolation cells
constexpr size_t CELL_BYTES   = (size_t)NCELL * 64;   // 2 MiB cell table
constexpr size_t PACKED_BYTES = (size_t)LUTSZ * 16;   // 575 KB (fallback)

typedef float        v4f __attribute__((ext_vector_type(4)));
typedef unsigned int v4u __attribute__((ext_vector_type(4)));

struct Rgb { float c0, c1, c2; };

__device__ __forceinline__ unsigned int pack_h2(float lo, float hi)
{
    __half2 h = __floats2half2_rn(lo, hi);
    return *reinterpret_cast<unsigned int*>(&h);
}

__device__ __forceinline__ float lerp_h2(unsigned int u, float w)
{
    __half2 h = *reinterpret_cast<__half2*>(&u);
    float lo = __half2float(__low2half(h));
    float hi = __half2float(__high2half(h));
    return fmaf(w, hi - lo, lo);
}

// ---------------------------------------------------------------------------
// Cell-pack kernel: for cell (i0,j0,k0) in [0,32)^3, entry = 64 B line:
//   uint4[0] = ch0 { (i0j0,k0k1), (i0j1,k0k1), (i1j0,k0k1), (i1j1,k0k1) }
//   uint4[1] = ch1 same, uint4[2] = ch2 same, uint4[3] = 0 pad
// Each pixel then needs exactly one 64-B line.
// ---------------------------------------------------------------------------
__global__ __launch_bounds__(256)
void pack_cells_kernel(const float* __restrict__ lut, v4u* __restrict__ T)
{
    int c = blockIdx.x * blockDim.x + threadIdx.x;
    if (c >= NCELL) return;
    int i0 = c >> 10, j0 = (c >> 5) & 31, k0 = c & 31;
    int base = (i0 * D + j0) * D + k0;

#pragma unroll
    for (int ch = 0; ch < 3; ++ch) {
        const float* __restrict__ L = lut + ch * LUTSZ;
        v4u e;
        e.x = pack_h2(L[base],             L[base + 1]);              // i0 j0
        e.y = pack_h2(L[base + D],         L[base + D + 1]);          // i0 j1
        e.z = pack_h2(L[base + D * D],     L[base + D * D + 1]);      // i1 j0
        e.w = pack_h2(L[base + D * D + D], L[base + D * D + D + 1]);  // i1 j1
        T[c * 4 + ch] = e;
    }
    T[c * 4 + 3] = (v4u)(0u);   // pad word, deterministic
}

__device__ __forceinline__ Rgb apply_lut_cell(const v4u* __restrict__ T,
                                              float r, float g, float b)
{
    float tr = fminf(fmaxf(r * 32.0f, 0.0f), 32.0f);
    float tg = fminf(fmaxf(g * 32.0f, 0.0f), 32.0f);
    float tb = fminf(fmaxf(b * 32.0f, 0.0f), 32.0f);

    // clamp low corner to 31: t==32 -> w=1.0 selects the high plane exactly
    int k0 = min((int)tr, 31); float wk = tr - (float)k0;
    int j0 = min((int)tg, 31); float wj = tg - (float)j0;
    int i0 = min((int)tb, 31); float wi = tb - (float)i0;

    int cell4 = (((i0 << 5) | j0) << 5 | k0) << 2;   // uint4 index of entry

    v4u e0 = T[cell4 + 0];
    v4u e1 = T[cell4 + 1];
    v4u e2 = T[cell4 + 2];

    Rgb o;
    {
        float c00 = lerp_h2(e0.x, wk), c01 = lerp_h2(e0.y, wk);
        float c10 = lerp_h2(e0.z, wk), c11 = lerp_h2(e0.w, wk);
        float c0 = fmaf(wj, c01 - c00, c00);
        float c1 = fmaf(wj, c11 - c10, c10);
        o.c0 = fmaf(wi, c1 - c0, c0);
    }
    {
        float c00 = lerp_h2(e1.x, wk), c01 = lerp_h2(e1.y, wk);
        float c10 = lerp_h2(e1.z, wk), c11 = lerp_h2(e1.w, wk);
        float c0 = fmaf(wj, c01 - c00, c00);
        float c1 = fmaf(wj, c11 - c10, c10);
        o.c1 = fmaf(wi, c1 - c0, c0);
    }
    {
        float c00 = lerp_h2(e2.x, wk), c01 = lerp_h2(e2.y, wk);
        float c10 = lerp_h2(e2.z, wk), c11 = lerp_h2(e2.w, wk);
        float c0 = fmaf(wj, c01 - c00, c00);
        float c1 = fmaf(wj, c11 - c10, c10);
        o.c2 = fmaf(wi, c1 - c0, c0);
    }
    return o;
}

__global__ __launch_bounds__(256)
void lut3d_cell_kernel(const float* __restrict__ x,
                       const v4u* __restrict__ T,
                       float* __restrict__ out)
{
    const int tid = blockIdx.x * blockDim.x + threadIdx.x;
    const int p0  = tid << 2;                 // 4 consecutive pixels
    const int b   = p0 >> 20;
    const int q   = p0 & (PLANE - 1);
    const int base = b * 3 * PLANE + q;

    const v4f rv = __builtin_nontemporal_load(reinterpret_cast<const v4f*>(x + base));
    const v4f gv = __builtin_nontemporal_load(reinterpret_cast<const v4f*>(x + base + PLANE));
    const v4f bv = __builtin_nontemporal_load(reinterpret_cast<const v4f*>(x + base + 2 * PLANE));

    Rgb p0r = apply_lut_cell(T, rv.x, gv.x, bv.x);
    Rgb p1r = apply_lut_cell(T, rv.y, gv.y, bv.y);
    Rgb p2r = apply_lut_cell(T, rv.z, gv.z, bv.z);
    Rgb p3r = apply_lut_cell(T, rv.w, gv.w, bv.w);

    v4f o0 = { p0r.c0, p1r.c0, p2r.c0, p3r.c0 };
    v4f o1 = { p0r.c1, p1r.c1, p2r.c1, p3r.c1 };
    v4f o2 = { p0r.c2, p1r.c2, p2r.c2, p3r.c2 };

    __builtin_nontemporal_store(o0, reinterpret_cast<v4f*>(out + base));
    __builtin_nontemporal_store(o1, reinterpret_cast<v4f*>(out + base + PLANE));
    __builtin_nontemporal_store(o2, reinterpret_cast<v4f*>(out + base + 2 * PLANE));
}

// ---------------------------------------------------------------------------
// Fallback: R4 packed-pair kernel (ws too small for cell table).
// ---------------------------------------------------------------------------
__global__ __launch_bounds__(256)
void pack_lut_kernel(const float* __restrict__ lut, v4u* __restrict__ P)
{
    int idx = blockIdx.x * blockDim.x + threadIdx.x;
    if (idx >= LUTSZ) return;
    int k = idx % D;
    v4u e = (v4u)(0u);
    if (k < D - 1) {
        e.x = pack_h2(lut[0 * LUTSZ + idx], lut[0 * LUTSZ + idx + 1]);
        e.y = pack_h2(lut[1 * LUTSZ + idx], lut[1 * LUTSZ + idx + 1]);
        e.z = pack_h2(lut[2 * LUTSZ + idx], lut[2 * LUTSZ + idx + 1]);
    }
    P[idx] = e;
}

__device__ __forceinline__ Rgb apply_lut_packed(const v4u* __restrict__ P,
                                                float r, float g, float b)
{
    float tr = fminf(fmaxf(r * 32.0f, 0.0f), 32.0f);
    float tg = fminf(fmaxf(g * 32.0f, 0.0f), 32.0f);
    float tb = fminf(fmaxf(b * 32.0f, 0.0f), 32.0f);
    int k0 = min((int)tr, D - 2); float wk = tr - (float)k0;
    int j0 = (int)tg; float wj = tg - (float)j0; int j1 = min(j0 + 1, D - 1);
    int i0 = (int)tb; float wi = tb - (float)i0; int i1 = min(i0 + 1, D - 1);
    v4u e00 = P[(i0 * D + j0) * D + k0];
    v4u e01 = P[(i0 * D + j1) * D + k0];
    v4u e10 = P[(i1 * D + j0) * D + k0];
    v4u e11 = P[(i1 * D + j1) * D + k0];
    Rgb o;
    {
        float c00 = lerp_h2(e00.x, wk), c01 = lerp_h2(e01.x, wk);
        float c10 = lerp_h2(e10.x, wk), c11 = lerp_h2(e11.x, wk);
        float c0 = fmaf(wj, c01 - c00, c00), c1 = fmaf(wj, c11 - c10, c10);
        o.c0 = fmaf(wi, c1 - c0, c0);
    }
    {
        float c00 = lerp_h2(e00.y, wk), c01 = lerp_h2(e01.y, wk);
        float c10 = lerp_h2(e10.y, wk), c11 = lerp_h2(e11.y, wk);
        float c0 = fmaf(wj, c01 - c00, c00), c1 = fmaf(wj, c11 - c10, c10);
        o.c1 = fmaf(wi, c1 - c0, c0);
    }
    {
        float c00 = lerp_h2(e00.z, wk), c01 = lerp_h2(e01.z, wk);
        float c10 = lerp_h2(e10.z, wk), c11 = lerp_h2(e11.z, wk);
        float c0 = fmaf(wj, c01 - c00, c00), c1 = fmaf(wj, c11 - c10, c10);
        o.c2 = fmaf(wi, c1 - c0, c0);
    }
    return o;
}

__global__ __launch_bounds__(256)
void lut3d_packed_kernel(const float* __restrict__ x,
                         const v4u* __restrict__ P,
                         float* __restrict__ out)
{
    const int tid = blockIdx.x * blockDim.x + threadIdx.x;
    const int p0  = tid << 2;
    const int b   = p0 >> 20;
    const int q   = p0 & (PLANE - 1);
    const int base = b * 3 * PLANE + q;
    const v4f rv = __builtin_nontemporal_load(reinterpret_cast<const v4f*>(x + base));
    const v4f gv = __builtin_nontemporal_load(reinterpret_cast<const v4f*>(x + base + PLANE));
    const v4f bv = __builtin_nontemporal_load(reinterpret_cast<const v4f*>(x + base + 2 * PLANE));
    Rgb p0r = apply_lut_packed(P, rv.x, gv.x, bv.x);
    Rgb p1r = apply_lut_packed(P, rv.y, gv.y, bv.y);
    Rgb p2r = apply_lut_packed(P, rv.z, gv.z, bv.z);
    Rgb p3r = apply_lut_packed(P, rv.w, gv.w, bv.w);
    v4f o0 = { p0r.c0, p1r.c0, p2r.c0, p3r.c0 };
    v4f o1 = { p0r.c1, p1r.c1, p2r.c1, p3r.c1 };
    v4f o2 = { p0r.c2, p1r.c2, p2r.c2, p3r.c2 };
    __builtin_nontemporal_store(o0, reinterpret_cast<v4f*>(out + base));
    __builtin_nontemporal_store(o1, reinterpret_cast<v4f*>(out + base + PLANE));
    __builtin_nontemporal_store(o2, reinterpret_cast<v4f*>(out + base + 2 * PLANE));
}

extern "C" void kernel_launch(void* const* d_in, const int* in_sizes, int n_in,
                              void* d_out, int out_size, void* d_ws, size_t ws_size,
                              hipStream_t stream)
{
    const float* x   = (const float*)d_in[0];
    const float* lut = (const float*)d_in[1];
    float* out       = (float*)d_out;

    const int n_threads = (BATCH * PLANE) / 4;   // 2,097,152
    dim3 block(256);
    dim3 grid(n_threads / 256);                  // 8192 blocks

    if (ws_size >= CELL_BYTES) {
        v4u* T = (v4u*)d_ws;
        pack_cells_kernel<<<NCELL / 256, 256, 0, stream>>>(lut, T);
        lut3d_cell_kernel<<<grid, block, 0, stream>>>(x, T, out);
    } else if (ws_size >= PACKED_BYTES) {
        v4u* P = (v4u*)d_ws;
        pack_lut_kernel<<<(LUTSZ + 255) / 256, 256, 0, stream>>>(lut, P);
        lut3d_packed_kernel<<<grid, block, 0, stream>>>(x, P, out);
    }
}